// Round 1
// baseline (1516.983 us; speedup 1.0000x reference)
//
#include <hip/hip_runtime.h>

typedef __attribute__((ext_vector_type(4))) float f32x4;
typedef __attribute__((ext_vector_type(8))) short short8;
typedef __attribute__((ext_vector_type(8))) unsigned short ushort8;
typedef unsigned short u16;
typedef unsigned int u32;

#define DMODEL 1024
#define DINNER 2048
#define NH     32
#define DIP    4288
#define CONVD  2176
#define LSEQ   2048
#define ROWS   8192
#define NCHUNK 32

static __device__ __forceinline__ float bf2f(u16 u) {
  u32 x = ((u32)u) << 16;
  return __builtin_bit_cast(float, x);
}
static __device__ __forceinline__ u16 f2bf(float f) {
  u32 x = __builtin_bit_cast(u32, f);
  x += 0x7fffu + ((x >> 16) & 1u);
  return (u16)(x >> 16);
}
static __device__ __forceinline__ f32x4 mfma16(short8 a, short8 b, f32x4 c) {
  return __builtin_amdgcn_mfma_f32_16x16x32_bf16(a, b, c, 0, 0, 0);
}

// ---------------- f32 -> bf16 weight cast (4 elems/thread, exact grid) ----------------
__global__ __launch_bounds__(256) void k_cast(const float* __restrict__ s, u16* __restrict__ d) {
  size_t i = ((size_t)blockIdx.x * 256 + threadIdx.x) * 4;
  float4 v = *(const float4*)(s + i);
  u32 lo = (u32)f2bf(v.x) | ((u32)f2bf(v.y) << 16);
  u32 hi = (u32)f2bf(v.z) | ((u32)f2bf(v.w) << 16);
  *(uint2*)(d + i) = make_uint2(lo, hi);
}

// ---------------- res = h + r ; hnorm = rmsnorm(res)*w (bf16) ----------------
__global__ __launch_bounds__(256) void k_addnorm(const float* __restrict__ h,
                                                 const float* __restrict__ r,
                                                 const float* __restrict__ nw,
                                                 float* __restrict__ res,
                                                 u16* __restrict__ hn) {
  int row = blockIdx.x, t = threadIdx.x;
  const float4* hp = (const float4*)(h + (size_t)row * DMODEL);
  const float4* rp = (const float4*)(r + (size_t)row * DMODEL);
  float4 a = hp[t], b = rp[t];
  float4 s;
  s.x = a.x + b.x; s.y = a.y + b.y; s.z = a.z + b.z; s.w = a.w + b.w;
  ((float4*)(res + (size_t)row * DMODEL))[t] = s;
  float ss = s.x * s.x + s.y * s.y + s.z * s.z + s.w * s.w;
  for (int m = 32; m; m >>= 1) ss += __shfl_xor(ss, m);
  __shared__ float wsum[4];
  if ((t & 63) == 0) wsum[t >> 6] = ss;
  __syncthreads();
  float tot = wsum[0] + wsum[1] + wsum[2] + wsum[3];
  float rinv = rsqrtf(tot * (1.0f / DMODEL) + 1e-5f);
  float4 w4 = ((const float4*)nw)[t];
  u32 lo = (u32)f2bf(s.x * rinv * w4.x) | ((u32)f2bf(s.y * rinv * w4.y) << 16);
  u32 hi = (u32)f2bf(s.z * rinv * w4.z) | ((u32)f2bf(s.w * rinv * w4.w) << 16);
  *(uint2*)(hn + (size_t)row * DMODEL + t * 4) = make_uint2(lo, hi);
}

// ---------------- bf16 MFMA GEMM: C[M,N] = A[M,K] @ W[N,K]^T ----------------
// 64x64 block tile, 4 waves (2x2), each wave 32x32 via 2x2 mfma_16x16x32.
// MODE 0: in_proj epilogue (split z / xBC / dt-with-flip+softplus)
// MODE 1: plain f32 output, N=1024
template <int MODE>
__global__ __launch_bounds__(256) void k_gemm(const u16* __restrict__ A,
                                              const u16* __restrict__ Bw, int K,
                                              float* __restrict__ outf,
                                              u16* __restrict__ zb, u16* __restrict__ xb,
                                              float* __restrict__ dtp,
                                              const float* __restrict__ dt_bias) {
  int wave = threadIdx.x >> 6, lane = threadIdx.x & 63;
  int wm = wave >> 1, wn = wave & 1;
  int lr = lane & 15;
  int lk = (lane >> 4) << 3;
  const u16* ap0 = A + (size_t)(blockIdx.x * 64 + wm * 32 + lr) * K + lk;
  const u16* bp0 = Bw + (size_t)(blockIdx.y * 64 + wn * 32 + lr) * K + lk;
  const u16* ap1 = ap0 + (size_t)16 * K;
  const u16* bp1 = bp0 + (size_t)16 * K;
  f32x4 acc[2][2] = {};
  for (int k0 = 0; k0 < K; k0 += 32) {
    short8 a0 = *(const short8*)(ap0 + k0);
    short8 a1 = *(const short8*)(ap1 + k0);
    short8 b0 = *(const short8*)(bp0 + k0);
    short8 b1 = *(const short8*)(bp1 + k0);
    acc[0][0] = mfma16(a0, b0, acc[0][0]);
    acc[0][1] = mfma16(a0, b1, acc[0][1]);
    acc[1][0] = mfma16(a1, b0, acc[1][0]);
    acc[1][1] = mfma16(a1, b1, acc[1][1]);
  }
  int mb = blockIdx.x * 64 + wm * 32 + (lane >> 4) * 4;
  int nb = blockIdx.y * 64 + wn * 32 + lr;
#pragma unroll
  for (int i = 0; i < 2; ++i)
#pragma unroll
    for (int j = 0; j < 2; ++j)
#pragma unroll
      for (int rr = 0; rr < 4; ++rr) {
        int m = mb + i * 16 + rr;
        int n = nb + j * 16;
        float v = acc[i][j][rr];
        if constexpr (MODE == 1) {
          outf[(size_t)m * 1024 + n] = v;
        } else {
          if (n < DINNER) {
            zb[(size_t)m * DINNER + n] = f2bf(v);
          } else if (n < DINNER + CONVD) {
            xb[(size_t)m * CONVD + (n - DINNER)] = f2bf(v);
          } else {
            int h2 = n - (DINNER + CONVD);           // 0..63
            float uu = v + dt_bias[h2 & 31];
            float sp = (uu > 20.f) ? uu : log1pf(expf(uu));
            int bb = m >> 11, tt = m & 2047;
            int obb = bb, ot = tt;
            if (h2 >= 32) { obb = bb + 4; ot = 2047 - tt; }
            dtp[((size_t)(obb << 11) + ot) * NH + (h2 & 31)] = sp;
          }
        }
      }
}

// ---------------- depthwise causal conv (k=4) + SiLU, split x/B/C ----------------
__global__ __launch_bounds__(256) void k_conv(const u16* __restrict__ xbc,
                                              const float* __restrict__ cw,
                                              const float* __restrict__ cb,
                                              u16* __restrict__ xc, u16* __restrict__ bm,
                                              u16* __restrict__ cm) {
  int e = blockIdx.x * 256 + threadIdx.x;
  int c = e % CONVD;
  int r = e / CONVD;
  int b = r >> 11, t = r & 2047;
  float acc = cb[c];
  const u16* col = xbc + (size_t)(b << 11) * CONVD + c;
#pragma unroll
  for (int k = 0; k < 4; ++k) {
    int tt = t - 3 + k;
    if (tt >= 0) acc += bf2f(col[(size_t)tt * CONVD]) * cw[c * 4 + k];
  }
  float s = acc * (1.f / (1.f + expf(-acc)));
  if (c < DINNER) xc[(size_t)r * DINNER + c] = f2bf(s);
  else if (c < DINNER + 64) bm[(size_t)r * 64 + (c - DINNER)] = f2bf(s);
  else cm[(size_t)r * 64 + (c - DINNER - 64)] = f2bf(s);
}

// ---------------- fused SSD scan: one block per (dir-batch, head) ----------------
// DIR 0: streams bb=0..3 (forward), plain store of y at t+1 (roll), zero row t=0.
// DIR 1: streams bb=4..7 (inputs read time-flipped), accumulate at final pos 2046-t.
template <int DIR>
__global__ __launch_bounds__(256) void k_ssd(const u16* __restrict__ xc,
                                             const u16* __restrict__ bmat,
                                             const u16* __restrict__ cmat,
                                             const float* __restrict__ dtp,
                                             const float* __restrict__ alog,
                                             u16* __restrict__ yb) {
  const int h = blockIdx.x & 31;
  const int bb = (blockIdx.x >> 5) + DIR * 4;
  const int tid = threadIdx.x, wave = tid >> 6, lane = tid & 63;
  const float Ah = -expf(alog[h]);

  __shared__ u16 sB[64][72];   // [s][n]
  __shared__ u16 sC[64][72];   // [s][n]
  __shared__ u16 sX[64][72];   // [s][p] (raw x, no dt)
  __shared__ u16 sM[64][72];   // [l][s] masked decay * G * dt
  __shared__ float sS[64][68]; // [p][n] running inter-chunk state (f32)
  __shared__ float sAc[64], sEA[64], sSc[64], sDt[64];

  for (int i = tid; i < 64 * 64; i += 256) sS[i >> 6][i & 63] = 0.f;

  const int lr = lane & 15, lg = lane >> 4;
  const int srow = tid >> 2, q = tid & 3;

  for (int c = 0; c < NCHUNK; ++c) {
    // ---- P0: stage B, C, X tiles + dt scan ----
    {
      int tdir = c * 64 + srow;
      int rg = (DIR == 0) ? (bb * LSEQ + tdir) : ((bb - 4) * LSEQ + (LSEQ - 1 - tdir));
      const u16* bsrc = bmat + (size_t)rg * 64 + q * 16;
      const u16* csrc = cmat + (size_t)rg * 64 + q * 16;
      const u16* xsrc = xc + (size_t)rg * DINNER + h * 64 + q * 16;
      *(ushort8*)&sB[srow][q * 16] = *(const ushort8*)bsrc;
      *(ushort8*)&sB[srow][q * 16 + 8] = *(const ushort8*)(bsrc + 8);
      *(ushort8*)&sC[srow][q * 16] = *(const ushort8*)csrc;
      *(ushort8*)&sC[srow][q * 16 + 8] = *(const ushort8*)(csrc + 8);
      *(ushort8*)&sX[srow][q * 16] = *(const ushort8*)xsrc;
      *(ushort8*)&sX[srow][q * 16 + 8] = *(const ushort8*)(xsrc + 8);
    }
    if (tid < 64) {
      int s = tid;
      float dv = dtp[((size_t)bb * LSEQ + c * 64 + s) * NH + h];
      float a = dv * Ah;
      float x = a;
#pragma unroll
      for (int d = 1; d < 64; d <<= 1) {
        float y = __shfl_up(x, d);
        if (s >= d) x += y;
      }
      float tot = __shfl(x, 63);
      sAc[s] = x;
      sEA[s] = expf(x);
      sSc[s] = expf(tot - x) * dv;   // decay * dt
      sDt[s] = dv;
    }
    __syncthreads();

    // ---- PA: G = C @ B^T  ->  M ;  Yoff = C @ S^T (reads S_prev) ----
    f32x4 acc_y[4] = {};
    {
      f32x4 acc_g[4] = {};
#pragma unroll
      for (int ks = 0; ks < 2; ++ks) {
        int kof = ks * 32 + lg * 8;
        short8 af = *(const short8*)&sC[wave * 16 + lr][kof];
#pragma unroll
        for (int nt = 0; nt < 4; ++nt) {
          short8 bf = *(const short8*)&sB[nt * 16 + lr][kof];
          acc_g[nt] = mfma16(af, bf, acc_g[nt]);
        }
      }
#pragma unroll
      for (int nt = 0; nt < 4; ++nt)
#pragma unroll
        for (int rr = 0; rr < 4; ++rr) {
          int l = wave * 16 + lg * 4 + rr;
          int s = nt * 16 + lr;
          float g = acc_g[nt][rr];
          float m = (l >= s) ? g * sDt[s] * expf(sAc[l] - sAc[s]) : 0.f;
          sM[l][s] = f2bf(m);
        }
#pragma unroll
      for (int ks = 0; ks < 2; ++ks) {
        int kof = ks * 32 + lg * 8;
        short8 af = *(const short8*)&sC[wave * 16 + lr][kof];
#pragma unroll
        for (int nt = 0; nt < 4; ++nt) {
          int p = nt * 16 + lr;
          short8 bf;
#pragma unroll
          for (int e = 0; e < 8; ++e) bf[e] = (short)f2bf(sS[p][kof + e]);
          acc_y[nt] = mfma16(af, bf, acc_y[nt]);
        }
      }
    }
    __syncthreads();

    // ---- PB: scale Yoff by exp(Acum); Ydiag = M @ X; write Y; state matmul; S update ----
#pragma unroll
    for (int nt = 0; nt < 4; ++nt)
#pragma unroll
      for (int rr = 0; rr < 4; ++rr) acc_y[nt][rr] *= sEA[wave * 16 + lg * 4 + rr];
#pragma unroll
    for (int ks = 0; ks < 2; ++ks) {
      int kof = ks * 32 + lg * 8;
      short8 af = *(const short8*)&sM[wave * 16 + lr][kof];
#pragma unroll
      for (int nt = 0; nt < 4; ++nt) {
        short8 bf;
#pragma unroll
        for (int e = 0; e < 8; ++e) bf[e] = (short)sX[kof + e][nt * 16 + lr];
        acc_y[nt] = mfma16(af, bf, acc_y[nt]);
      }
    }
#pragma unroll
    for (int nt = 0; nt < 4; ++nt)
#pragma unroll
      for (int rr = 0; rr < 4; ++rr) {
        int l = wave * 16 + lg * 4 + rr;
        int p = nt * 16 + lr;
        int tg = c * 64 + l;
        float v = acc_y[nt][rr];
        if (DIR == 0) {
          int tp = tg + 1;
          if (tp < LSEQ) yb[((size_t)bb * LSEQ + tp) * DINNER + h * 64 + p] = f2bf(v);
        } else {
          if (tg <= LSEQ - 2) {
            size_t ix = ((size_t)(bb - 4) * LSEQ + (LSEQ - 2 - tg)) * DINNER + h * 64 + p;
            yb[ix] = f2bf(bf2f(yb[ix]) + v);
          }
        }
      }
    if (DIR == 0 && c == 0 && wave == 0 && lane < 16) {
#pragma unroll
      for (int qq = 0; qq < 4; ++qq)
        yb[((size_t)bb * LSEQ) * DINNER + h * 64 + qq * 16 + lane] = 0;
    }
    // chunk state: S_new = exp(Asum)*S + X^T(diag(decay*dt)) B
    {
      f32x4 acc_s[4] = {};
#pragma unroll
      for (int ks = 0; ks < 2; ++ks) {
        int kof = ks * 32 + lg * 8;
        short8 af;
#pragma unroll
        for (int e = 0; e < 8; ++e) {
          int s = kof + e;
          af[e] = (short)f2bf(bf2f(sX[s][wave * 16 + lr]) * sSc[s]);
        }
#pragma unroll
        for (int nt = 0; nt < 4; ++nt) {
          short8 bf;
#pragma unroll
          for (int e = 0; e < 8; ++e) bf[e] = (short)sB[kof + e][nt * 16 + lr];
          acc_s[nt] = mfma16(af, bf, acc_s[nt]);
        }
      }
      float lam = sEA[63];
#pragma unroll
      for (int nt = 0; nt < 4; ++nt)
#pragma unroll
        for (int rr = 0; rr < 4; ++rr) {
          int p = wave * 16 + lg * 4 + rr;
          int n = nt * 16 + lr;
          sS[p][n] = lam * sS[p][n] + acc_s[nt][rr];
        }
    }
    __syncthreads();
  }
}

// ---------------- Deff = x @ fc_D_w^T + D ----------------
__global__ __launch_bounds__(64) void k_deff(const u16* __restrict__ xcv,
                                             const float* __restrict__ fw,
                                             const float* __restrict__ Dv,
                                             float* __restrict__ deff) {
  int r = blockIdx.x * 2 + (threadIdx.x >> 5);
  int hh = threadIdx.x & 31;
  const u16* xr = xcv + (size_t)r * DINNER;
  const float* fr = fw + (size_t)hh * DINNER;
  float acc = 0.f;
  for (int k = 0; k < DINNER; k += 8) {
    ushort8 xv = *(const ushort8*)(xr + k);
    float4 f0 = *(const float4*)(fr + k);
    float4 f1 = *(const float4*)(fr + k + 4);
    acc += bf2f(xv[0]) * f0.x + bf2f(xv[1]) * f0.y + bf2f(xv[2]) * f0.z + bf2f(xv[3]) * f0.w +
           bf2f(xv[4]) * f1.x + bf2f(xv[5]) * f1.y + bf2f(xv[6]) * f1.z + bf2f(xv[7]) * f1.w;
  }
  deff[(size_t)r * NH + hh] = acc + Dv[hh];
}

// ---------------- gating: yn = rmsnorm((y + x*Deff) * silu(z)) * gnw ----------------
__global__ __launch_bounds__(256) void k_gate(const u16* __restrict__ yb,
                                              const u16* __restrict__ xcv,
                                              const float* __restrict__ deff,
                                              const u16* __restrict__ zb,
                                              const float* __restrict__ gnw,
                                              u16* __restrict__ yn) {
  int row = blockIdx.x, t = threadIdx.x;
  size_t base = (size_t)row * DINNER + t * 8;
  ushort8 yv = *(const ushort8*)(yb + base);
  ushort8 xv = *(const ushort8*)(xcv + base);
  ushort8 zv = *(const ushort8*)(zb + base);
  float de = deff[row * NH + (t >> 3)];
  float g[8];
  float ss = 0.f;
#pragma unroll
  for (int j = 0; j < 8; ++j) {
    float y = bf2f(yv[j]) + bf2f(xv[j]) * de;
    float z = bf2f(zv[j]);
    float gg = y * (z / (1.f + expf(-z)));
    g[j] = gg;
    ss += gg * gg;
  }
  for (int m = 32; m; m >>= 1) ss += __shfl_xor(ss, m);
  __shared__ float wsum[4];
  if ((t & 63) == 0) wsum[t >> 6] = ss;
  __syncthreads();
  float tot = wsum[0] + wsum[1] + wsum[2] + wsum[3];
  float rinv = rsqrtf(tot * (1.0f / DINNER) + 1e-5f);
  u32 w0 = 0, w1 = 0, w2 = 0, w3 = 0;
  w0 = (u32)f2bf(g[0] * rinv * gnw[t * 8 + 0]) | ((u32)f2bf(g[1] * rinv * gnw[t * 8 + 1]) << 16);
  w1 = (u32)f2bf(g[2] * rinv * gnw[t * 8 + 2]) | ((u32)f2bf(g[3] * rinv * gnw[t * 8 + 3]) << 16);
  w2 = (u32)f2bf(g[4] * rinv * gnw[t * 8 + 4]) | ((u32)f2bf(g[5] * rinv * gnw[t * 8 + 5]) << 16);
  w3 = (u32)f2bf(g[6] * rinv * gnw[t * 8 + 6]) | ((u32)f2bf(g[7] * rinv * gnw[t * 8 + 7]) << 16);
  *(uint4*)(yn + base) = make_uint4(w0, w1, w2, w3);
}

extern "C" void kernel_launch(void* const* d_in, const int* in_sizes, int n_in,
                              void* d_out, int out_size, void* d_ws, size_t ws_size,
                              hipStream_t stream) {
  (void)in_sizes; (void)n_in; (void)out_size; (void)ws_size;
  const float* hid = (const float*)d_in[0];
  const float* resin = (const float*)d_in[1];
  const float* nw = (const float*)d_in[2];
  const float* w1 = (const float*)d_in[3];
  const float* cw = (const float*)d_in[4];
  const float* cb = (const float*)d_in[5];
  const float* dtb = (const float*)d_in[6];
  const float* alog = (const float*)d_in[7];
  const float* Dv = (const float*)d_in[8];
  const float* fcw = (const float*)d_in[9];
  const float* gnw = (const float*)d_in[10];
  const float* w2 = (const float*)d_in[11];
  float* out = (float*)d_out;
  float* resout = out + (size_t)ROWS * DMODEL;

  char* ws = (char*)d_ws;
  size_t o = 0;
  auto alloc = [&](size_t bytes) {
    char* p = ws + o;
    o += (bytes + 255) & ~(size_t)255;
    return p;
  };
  u16* W1b = (u16*)alloc((size_t)DIP * DMODEL * 2);      // 8.8 MB (reused for W2b)
  u16* HN = (u16*)alloc((size_t)ROWS * DMODEL * 2);      // 16 MB (reused for YN)
  u16* XBC = (u16*)alloc((size_t)ROWS * CONVD * 2);      // 35.7 MB (reused for YB)
  u16* ZB = (u16*)alloc((size_t)ROWS * DINNER * 2);      // 33.6 MB
  u16* XC = (u16*)alloc((size_t)ROWS * DINNER * 2);      // 33.6 MB
  u16* BM = (u16*)alloc((size_t)ROWS * 64 * 2);          // 1 MB
  u16* CM = (u16*)alloc((size_t)ROWS * 64 * 2);          // 1 MB
  float* DT = (float*)alloc((size_t)8 * LSEQ * NH * 4);  // 2 MB
  float* DE = (float*)alloc((size_t)ROWS * NH * 4);      // 1 MB
  // total ~127.4 MiB
  u16* YB = XBC;
  u16* W2b = W1b;
  u16* YN = HN;

  k_cast<<<(DIP * DMODEL) / 1024, 256, 0, stream>>>(w1, W1b);
  k_addnorm<<<ROWS, 256, 0, stream>>>(hid, resin, nw, resout, HN);
  k_gemm<0><<<dim3(ROWS / 64, DIP / 64), 256, 0, stream>>>(HN, W1b, DMODEL, nullptr, ZB, XBC,
                                                           DT, dtb);
  k_conv<<<(ROWS * CONVD) / 256, 256, 0, stream>>>(XBC, cw, cb, XC, BM, CM);
  k_ssd<0><<<128, 256, 0, stream>>>(XC, BM, CM, DT, alog, YB);
  k_ssd<1><<<128, 256, 0, stream>>>(XC, BM, CM, DT, alog, YB);
  k_cast<<<(DMODEL * DINNER) / 1024, 256, 0, stream>>>(w2, W2b);
  k_deff<<<ROWS / 2, 64, 0, stream>>>(XC, fcw, Dv, DE);
  k_gate<<<ROWS, 256, 0, stream>>>(YB, XC, DE, ZB, gnw, YN);
  k_gemm<1><<<dim3(ROWS / 64, DMODEL / 64), 256, 0, stream>>>(YN, W2b, DINNER, out, nullptr,
                                                              nullptr, nullptr, nullptr);
}

// Round 2
// 851.504 us; speedup vs baseline: 1.7815x; 1.7815x over previous
//
#include <hip/hip_runtime.h>

typedef __attribute__((ext_vector_type(4))) float f32x4;
typedef __attribute__((ext_vector_type(8))) short short8;
typedef __attribute__((ext_vector_type(8))) unsigned short ushort8;
typedef unsigned short u16;
typedef unsigned int u32;

#define DMODEL 1024
#define DINNER 2048
#define NH     32
#define DIP    4288
#define DIP_PAD 4352
#define CONVD  2176
#define LSEQ   2048
#define ROWS   8192
#define NCHUNK 32

static __device__ __forceinline__ float bf2f(u16 u) {
  u32 x = ((u32)u) << 16;
  return __builtin_bit_cast(float, x);
}
static __device__ __forceinline__ u16 f2bf(float f) {
  u32 x = __builtin_bit_cast(u32, f);
  x += 0x7fffu + ((x >> 16) & 1u);
  return (u16)(x >> 16);
}
static __device__ __forceinline__ f32x4 mfma16(short8 a, short8 b, f32x4 c) {
  return __builtin_amdgcn_mfma_f32_16x16x32_bf16(a, b, c, 0, 0, 0);
}

#define GLDS(gp, lp)                                                     \
  __builtin_amdgcn_global_load_lds(                                     \
      (const __attribute__((address_space(1))) void*)(gp),              \
      (__attribute__((address_space(3))) void*)(lp), 16, 0, 0)

// ---------------- f32 -> bf16 weight cast ----------------
__global__ __launch_bounds__(256) void k_cast(const float* __restrict__ s, u16* __restrict__ d) {
  size_t i = ((size_t)blockIdx.x * 256 + threadIdx.x) * 4;
  float4 v = *(const float4*)(s + i);
  u32 lo = (u32)f2bf(v.x) | ((u32)f2bf(v.y) << 16);
  u32 hi = (u32)f2bf(v.z) | ((u32)f2bf(v.w) << 16);
  *(uint2*)(d + i) = make_uint2(lo, hi);
}

// ---------------- res = h + r ; hnorm = rmsnorm(res)*w (bf16) ----------------
__global__ __launch_bounds__(256) void k_addnorm(const float* __restrict__ h,
                                                 const float* __restrict__ r,
                                                 const float* __restrict__ nw,
                                                 float* __restrict__ res,
                                                 u16* __restrict__ hn) {
  int row = blockIdx.x, t = threadIdx.x;
  const float4* hp = (const float4*)(h + (size_t)row * DMODEL);
  const float4* rp = (const float4*)(r + (size_t)row * DMODEL);
  float4 a = hp[t], b = rp[t];
  float4 s;
  s.x = a.x + b.x; s.y = a.y + b.y; s.z = a.z + b.z; s.w = a.w + b.w;
  ((float4*)(res + (size_t)row * DMODEL))[t] = s;
  float ss = s.x * s.x + s.y * s.y + s.z * s.z + s.w * s.w;
  for (int m = 32; m; m >>= 1) ss += __shfl_xor(ss, m);
  __shared__ float wsum[4];
  if ((t & 63) == 0) wsum[t >> 6] = ss;
  __syncthreads();
  float tot = wsum[0] + wsum[1] + wsum[2] + wsum[3];
  float rinv = rsqrtf(tot * (1.0f / DMODEL) + 1e-5f);
  float4 w4 = ((const float4*)nw)[t];
  u32 lo = (u32)f2bf(s.x * rinv * w4.x) | ((u32)f2bf(s.y * rinv * w4.y) << 16);
  u32 hi = (u32)f2bf(s.z * rinv * w4.z) | ((u32)f2bf(s.w * rinv * w4.w) << 16);
  *(uint2*)(hn + (size_t)row * DMODEL + t * 4) = make_uint2(lo, hi);
}

// ---------------- LDS-staged bf16 MFMA GEMM (m97 structure) ----------------
// 128x128 tile, BK=32, 4 waves (2x2), each wave 64x64 via 4x4 mfma_16x16x32.
// global_load_lds width=16 staging; A[M,K] @ Bw[N,K]^T.
template <int MODE>
__global__ __launch_bounds__(256) void k_gemm(const u16* __restrict__ A,
                                              const u16* __restrict__ Bw, int K,
                                              float* __restrict__ outf,
                                              u16* __restrict__ zb, u16* __restrict__ xb,
                                              float* __restrict__ dtp,
                                              const float* __restrict__ dt_bias) {
  __shared__ u16 sA[128 * 32];
  __shared__ u16 sB[128 * 32];
  const int tid = threadIdx.x, wave = tid >> 6;
  const int lane = tid & 63;
  const int wm = wave >> 1, wn = wave & 1;
  const int lr = lane & 15, lg = lane >> 4;
  const int brow = blockIdx.x * 128, bcol = blockIdx.y * 128;
  const int srow = tid >> 2, scol = (tid & 3) * 8;
  const u16* gA = A + (size_t)(brow + srow) * K + scol;
  const u16* gB = Bw + (size_t)(bcol + srow) * K + scol;
  const size_t rstep = (size_t)64 * K;
  char* lA = (char*)sA + wave * 1024;
  char* lB = (char*)sB + wave * 1024;

  f32x4 acc[4][4] = {};
  for (int k0 = 0; k0 < K; k0 += 32) {
    __syncthreads();
    GLDS(gA + k0, lA);
    GLDS(gA + rstep + k0, lA + 4096);
    GLDS(gB + k0, lB);
    GLDS(gB + rstep + k0, lB + 4096);
    __syncthreads();
    short8 af[4], bf[4];
#pragma unroll
    for (int i = 0; i < 4; ++i) {
      af[i] = *(const short8*)&sA[(wm * 64 + i * 16 + lr) * 32 + lg * 8];
      bf[i] = *(const short8*)&sB[(wn * 64 + i * 16 + lr) * 32 + lg * 8];
    }
#pragma unroll
    for (int i = 0; i < 4; ++i)
#pragma unroll
      for (int j = 0; j < 4; ++j) acc[i][j] = mfma16(af[i], bf[j], acc[i][j]);
  }

  const int mb = brow + wm * 64 + lg * 4;
  const int nb = bcol + wn * 64 + lr;
#pragma unroll
  for (int i = 0; i < 4; ++i)
#pragma unroll
    for (int j = 0; j < 4; ++j)
#pragma unroll
      for (int rr = 0; rr < 4; ++rr) {
        int m = mb + i * 16 + rr;
        int n = nb + j * 16;
        float v = acc[i][j][rr];
        if constexpr (MODE == 1) {
          outf[(size_t)m * 1024 + n] = v;
        } else {
          if (n < DINNER) {
            zb[(size_t)m * DINNER + n] = f2bf(v);
          } else if (n < DINNER + CONVD) {
            xb[(size_t)m * CONVD + (n - DINNER)] = f2bf(v);
          } else if (n < DIP) {
            int h2 = n - (DINNER + CONVD);  // 0..63
            float uu = v + dt_bias[h2 & 31];
            float sp = (uu > 20.f) ? uu : log1pf(expf(uu));
            int bb = m >> 11, tt = m & 2047;
            int obb = bb, ot = tt;
            if (h2 >= 32) { obb = bb + 4; ot = 2047 - tt; }
            dtp[((size_t)(obb << 11) + ot) * NH + (h2 & 31)] = sp;
          }
        }
      }
}

// ---------------- depthwise causal conv (k=4) + SiLU, 8 chans/thread ----------------
__global__ __launch_bounds__(256) void k_conv(const u16* __restrict__ xbc,
                                              const float* __restrict__ cw,
                                              const float* __restrict__ cb,
                                              u16* __restrict__ xc, u16* __restrict__ bm,
                                              u16* __restrict__ cm) {
  int e = blockIdx.x * 256 + threadIdx.x;  // e < ROWS*272
  int c8 = e % 272;
  int r = e / 272;
  int c = c8 * 8;
  int b = r >> 11, t = r & 2047;
  float4 w[8];
  float a[8];
#pragma unroll
  for (int j = 0; j < 8; ++j) {
    w[j] = *(const float4*)&cw[(c + j) * 4];
    a[j] = cb[c + j];
  }
  const u16* base = xbc + (size_t)(b << 11) * CONVD + c;
#pragma unroll
  for (int k = 0; k < 4; ++k) {
    int tt = t - 3 + k;
    if (tt >= 0) {
      ushort8 v = *(const ushort8*)(base + (size_t)tt * CONVD);
#pragma unroll
      for (int j = 0; j < 8; ++j) a[j] += bf2f(v[j]) * ((const float*)&w[j])[k];
    }
  }
  ushort8 o;
#pragma unroll
  for (int j = 0; j < 8; ++j) {
    float s = a[j] * (1.f / (1.f + expf(-a[j])));
    o[j] = f2bf(s);
  }
  if (c8 < 256) *(ushort8*)(xc + (size_t)r * DINNER + c) = o;
  else if (c8 < 264) *(ushort8*)(bm + (size_t)r * 64 + (c - DINNER)) = o;
  else *(ushort8*)(cm + (size_t)r * 64 + (c - DINNER - 64)) = o;
}

// ---------------- fused SSD scan: one block per (dir, batch, head) ----------------
// dir 0 -> y0 (roll: store at t+1, zero t=0); dir 1 -> y1 (store at 2046-t, zero t=2047).
__global__ __launch_bounds__(256) void k_ssd(const u16* __restrict__ xc,
                                             const u16* __restrict__ bmat,
                                             const u16* __restrict__ cmat,
                                             const float* __restrict__ dtp,
                                             const float* __restrict__ alog,
                                             u16* __restrict__ y0, u16* __restrict__ y1) {
  const int h = blockIdx.x & 31;
  const int grp = blockIdx.x >> 5;  // 0..7
  const int dir = grp >> 2;
  const int bt = grp & 3;
  const int tid = threadIdx.x, wave = tid >> 6, lane = tid & 63;
  const float Ah = -expf(alog[h]);

  __shared__ u16 sB[64][72];   // [s][n]
  __shared__ u16 sC[64][72];   // [s][n]
  __shared__ u16 sXM[64][72];  // staged X [s][p]; after transpose reused as M [l][s]
  __shared__ u16 sXT[64][72];  // X^T [p][s]
  __shared__ u16 sBT[64][72];  // B^T [n][s]
  __shared__ float sS[64][68]; // [p][n] running inter-chunk state (f32)
  __shared__ float sAc[64], sEA[64], sSc[64], sDt[64];

  for (int i = tid; i < 64 * 64; i += 256) sS[i >> 6][i & 63] = 0.f;

  const int lr = lane & 15, lg = lane >> 4;
  const int srow = tid >> 2, q = tid & 3;
  const int tp = tid >> 2, ts0 = (tid & 3) << 4;  // transpose mapping

  for (int c = 0; c < NCHUNK; ++c) {
    // ---- P0: stage B, C, X tiles + dt scan ----
    {
      int tdir = c * 64 + srow;
      int rg = bt * LSEQ + (dir ? (LSEQ - 1 - tdir) : tdir);
      const u16* bsrc = bmat + (size_t)rg * 64 + q * 16;
      const u16* csrc = cmat + (size_t)rg * 64 + q * 16;
      const u16* xsrc = xc + (size_t)rg * DINNER + h * 64 + q * 16;
      *(ushort8*)&sB[srow][q * 16] = *(const ushort8*)bsrc;
      *(ushort8*)&sB[srow][q * 16 + 8] = *(const ushort8*)(bsrc + 8);
      *(ushort8*)&sC[srow][q * 16] = *(const ushort8*)csrc;
      *(ushort8*)&sC[srow][q * 16 + 8] = *(const ushort8*)(csrc + 8);
      *(ushort8*)&sXM[srow][q * 16] = *(const ushort8*)xsrc;
      *(ushort8*)&sXM[srow][q * 16 + 8] = *(const ushort8*)(xsrc + 8);
    }
    if (tid < 64) {
      int s = tid;
      float dv = dtp[((size_t)grp * LSEQ + c * 64 + s) * NH + h];
      float a = dv * Ah;
      float x = a;
#pragma unroll
      for (int d = 1; d < 64; d <<= 1) {
        float y = __shfl_up(x, d);
        if (s >= d) x += y;
      }
      float tot = __shfl(x, 63);
      sAc[s] = x;
      sEA[s] = expf(x);
      sSc[s] = expf(tot - x) * dv;  // decay * dt
      sDt[s] = dv;
    }
    __syncthreads();

    // ---- P0b: transpose X and B into row-readable layouts ----
    {
      ushort8 vx0, vx1, vb0, vb1;
#pragma unroll
      for (int i = 0; i < 8; ++i) {
        vx0[i] = sXM[ts0 + i][tp];
        vx1[i] = sXM[ts0 + 8 + i][tp];
        vb0[i] = sB[ts0 + i][tp];
        vb1[i] = sB[ts0 + 8 + i][tp];
      }
      *(ushort8*)&sXT[tp][ts0] = vx0;
      *(ushort8*)&sXT[tp][ts0 + 8] = vx1;
      *(ushort8*)&sBT[tp][ts0] = vb0;
      *(ushort8*)&sBT[tp][ts0 + 8] = vb1;
    }
    __syncthreads();

    // ---- PA: G = C @ B^T -> M (into sXM); Yoff = C @ S_prev^T ----
    f32x4 acc_y[4] = {};
    {
      f32x4 acc_g[4] = {};
#pragma unroll
      for (int ks = 0; ks < 2; ++ks) {
        int kof = ks * 32 + lg * 8;
        short8 af = *(const short8*)&sC[wave * 16 + lr][kof];
#pragma unroll
        for (int nt = 0; nt < 4; ++nt) {
          short8 bf = *(const short8*)&sB[nt * 16 + lr][kof];
          acc_g[nt] = mfma16(af, bf, acc_g[nt]);
        }
      }
#pragma unroll
      for (int ks = 0; ks < 2; ++ks) {
        int kof = ks * 32 + lg * 8;
        short8 af = *(const short8*)&sC[wave * 16 + lr][kof];
#pragma unroll
        for (int nt = 0; nt < 4; ++nt) {
          const float* sr = &sS[nt * 16 + lr][kof];
          f32x4 s0 = *(const f32x4*)sr;
          f32x4 s1 = *(const f32x4*)(sr + 4);
          short8 bf;
#pragma unroll
          for (int e = 0; e < 4; ++e) {
            bf[e] = (short)f2bf(s0[e]);
            bf[e + 4] = (short)f2bf(s1[e]);
          }
          acc_y[nt] = mfma16(af, bf, acc_y[nt]);
        }
      }
      // masked decay matrix M[l][s] -> sXM (sXM's X content is dead: sXT holds it)
#pragma unroll
      for (int nt = 0; nt < 4; ++nt)
#pragma unroll
        for (int rr = 0; rr < 4; ++rr) {
          int l = wave * 16 + lg * 4 + rr;
          int s = nt * 16 + lr;
          float g = acc_g[nt][rr];
          float m = (l >= s) ? g * sDt[s] * expf(sAc[l] - sAc[s]) : 0.f;
          sXM[l][s] = f2bf(m);
        }
    }
    __syncthreads();

    // ---- PB: Y = Yoff*exp(Acum) + M @ X; write Y; S update ----
#pragma unroll
    for (int nt = 0; nt < 4; ++nt)
#pragma unroll
      for (int rr = 0; rr < 4; ++rr) acc_y[nt][rr] *= sEA[wave * 16 + lg * 4 + rr];
#pragma unroll
    for (int ks = 0; ks < 2; ++ks) {
      int kof = ks * 32 + lg * 8;
      short8 af = *(const short8*)&sXM[wave * 16 + lr][kof];
#pragma unroll
      for (int nt = 0; nt < 4; ++nt) {
        short8 bf = *(const short8*)&sXT[nt * 16 + lr][kof];
        acc_y[nt] = mfma16(af, bf, acc_y[nt]);
      }
    }
#pragma unroll
    for (int nt = 0; nt < 4; ++nt)
#pragma unroll
      for (int rr = 0; rr < 4; ++rr) {
        int l = wave * 16 + lg * 4 + rr;
        int p = nt * 16 + lr;
        int tg = c * 64 + l;
        if (tg <= LSEQ - 2) {
          float v = acc_y[nt][rr];
          if (dir == 0)
            y0[((size_t)bt * LSEQ + tg + 1) * DINNER + h * 64 + p] = f2bf(v);
          else
            y1[((size_t)bt * LSEQ + (LSEQ - 2 - tg)) * DINNER + h * 64 + p] = f2bf(v);
        }
      }
    if (c == 0 && tid < 64) {
      if (dir == 0)
        y0[((size_t)bt * LSEQ) * DINNER + h * 64 + tid] = 0;
      else
        y1[((size_t)bt * LSEQ + (LSEQ - 1)) * DINNER + h * 64 + tid] = 0;
    }
    // chunk state: S_new = exp(Asum)*S + (X*decay*dt)^T @ B
    {
      f32x4 acc_s[4] = {};
#pragma unroll
      for (int ks = 0; ks < 2; ++ks) {
        int kof = ks * 32 + lg * 8;
        ushort8 xr = *(const ushort8*)&sXT[wave * 16 + lr][kof];
        short8 af;
#pragma unroll
        for (int e = 0; e < 8; ++e) af[e] = (short)f2bf(bf2f(xr[e]) * sSc[kof + e]);
#pragma unroll
        for (int nt = 0; nt < 4; ++nt) {
          short8 bf = *(const short8*)&sBT[nt * 16 + lr][kof];
          acc_s[nt] = mfma16(af, bf, acc_s[nt]);
        }
      }
      float lam = sEA[63];
#pragma unroll
      for (int nt = 0; nt < 4; ++nt)
#pragma unroll
        for (int rr = 0; rr < 4; ++rr) {
          int p = wave * 16 + lg * 4 + rr;
          int n = nt * 16 + lr;
          sS[p][n] = lam * sS[p][n] + acc_s[nt][rr];
        }
    }
    __syncthreads();
  }
}

// ---------------- Deff = x @ fc_D_w^T + D ----------------
__global__ __launch_bounds__(64) void k_deff(const u16* __restrict__ xcv,
                                             const float* __restrict__ fw,
                                             const float* __restrict__ Dv,
                                             float* __restrict__ deff) {
  int r = blockIdx.x * 2 + (threadIdx.x >> 5);
  int hh = threadIdx.x & 31;
  const u16* xr = xcv + (size_t)r * DINNER;
  const float* fr = fw + (size_t)hh * DINNER;
  float acc = 0.f;
  for (int k = 0; k < DINNER; k += 8) {
    ushort8 xv = *(const ushort8*)(xr + k);
    float4 f0 = *(const float4*)(fr + k);
    float4 f1 = *(const float4*)(fr + k + 4);
    acc += bf2f(xv[0]) * f0.x + bf2f(xv[1]) * f0.y + bf2f(xv[2]) * f0.z + bf2f(xv[3]) * f0.w +
           bf2f(xv[4]) * f1.x + bf2f(xv[5]) * f1.y + bf2f(xv[6]) * f1.z + bf2f(xv[7]) * f1.w;
  }
  deff[(size_t)r * NH + hh] = acc + Dv[hh];
}

// ---------------- gating: yn = rmsnorm((y0 + y1 + x*Deff) * silu(z)) * gnw ----------------
__global__ __launch_bounds__(256) void k_gate(const u16* __restrict__ yb0,
                                              const u16* __restrict__ yb1,
                                              const u16* __restrict__ xcv,
                                              const float* __restrict__ deff,
                                              const u16* __restrict__ zb,
                                              const float* __restrict__ gnw,
                                              u16* __restrict__ yn) {
  int row = blockIdx.x, t = threadIdx.x;
  size_t base = (size_t)row * DINNER + t * 8;
  ushort8 y0v = *(const ushort8*)(yb0 + base);
  ushort8 y1v = *(const ushort8*)(yb1 + base);
  ushort8 xv = *(const ushort8*)(xcv + base);
  ushort8 zv = *(const ushort8*)(zb + base);
  float de = deff[row * NH + (t >> 3)];
  float g[8];
  float ss = 0.f;
#pragma unroll
  for (int j = 0; j < 8; ++j) {
    float y = bf2f(y0v[j]) + bf2f(y1v[j]) + bf2f(xv[j]) * de;
    float z = bf2f(zv[j]);
    float gg = y * (z / (1.f + expf(-z)));
    g[j] = gg;
    ss += gg * gg;
  }
  for (int m = 32; m; m >>= 1) ss += __shfl_xor(ss, m);
  __shared__ float wsum[4];
  if ((t & 63) == 0) wsum[t >> 6] = ss;
  __syncthreads();
  float tot = wsum[0] + wsum[1] + wsum[2] + wsum[3];
  float rinv = rsqrtf(tot * (1.0f / DINNER) + 1e-5f);
  u32 w0 = (u32)f2bf(g[0] * rinv * gnw[t * 8 + 0]) | ((u32)f2bf(g[1] * rinv * gnw[t * 8 + 1]) << 16);
  u32 w1 = (u32)f2bf(g[2] * rinv * gnw[t * 8 + 2]) | ((u32)f2bf(g[3] * rinv * gnw[t * 8 + 3]) << 16);
  u32 w2 = (u32)f2bf(g[4] * rinv * gnw[t * 8 + 4]) | ((u32)f2bf(g[5] * rinv * gnw[t * 8 + 5]) << 16);
  u32 w3 = (u32)f2bf(g[6] * rinv * gnw[t * 8 + 6]) | ((u32)f2bf(g[7] * rinv * gnw[t * 8 + 7]) << 16);
  *(uint4*)(yn + base) = make_uint4(w0, w1, w2, w3);
}

extern "C" void kernel_launch(void* const* d_in, const int* in_sizes, int n_in,
                              void* d_out, int out_size, void* d_ws, size_t ws_size,
                              hipStream_t stream) {
  (void)in_sizes; (void)n_in; (void)out_size; (void)ws_size;
  const float* hid = (const float*)d_in[0];
  const float* resin = (const float*)d_in[1];
  const float* nw = (const float*)d_in[2];
  const float* w1 = (const float*)d_in[3];
  const float* cw = (const float*)d_in[4];
  const float* cb = (const float*)d_in[5];
  const float* dtb = (const float*)d_in[6];
  const float* alog = (const float*)d_in[7];
  const float* Dv = (const float*)d_in[8];
  const float* fcw = (const float*)d_in[9];
  const float* gnw = (const float*)d_in[10];
  const float* w2 = (const float*)d_in[11];
  float* out = (float*)d_out;
  float* resout = out + (size_t)ROWS * DMODEL;

  char* ws = (char*)d_ws;
  size_t o = 0;
  auto alloc = [&](size_t bytes) {
    char* p = ws + o;
    o += (bytes + 255) & ~(size_t)255;
    return p;
  };
  u16* W1b = (u16*)alloc((size_t)DIP_PAD * DMODEL * 2);  // 8.9 MB (reused for W2b)
  u16* HN = (u16*)alloc((size_t)ROWS * DMODEL * 2);      // 16.8 MB (reused for YN)
  u16* XBC = (u16*)alloc((size_t)ROWS * CONVD * 2);      // 35.7 MB (reused for YB0)
  u16* ZB = (u16*)alloc((size_t)ROWS * DINNER * 2);      // 33.6 MB
  u16* XC = (u16*)alloc((size_t)ROWS * DINNER * 2);      // 33.6 MB
  u16* BM = (u16*)alloc((size_t)ROWS * 64 * 2);          // 1 MB
  u16* CM = (u16*)alloc((size_t)ROWS * 64 * 2);          // 1 MB
  float* DT = (float*)alloc((size_t)8 * LSEQ * NH * 4);  // 2 MB
  float* DE = (float*)alloc((size_t)ROWS * NH * 4);      // 1 MB
  u16* YB0 = XBC;
  u16* YB1 = (u16*)out;  // out region (33.55 MB) is dead until final GEMM
  u16* W2b = W1b;
  u16* YN = HN;

  k_cast<<<(DIP * DMODEL) / 1024, 256, 0, stream>>>(w1, W1b);
  k_addnorm<<<ROWS, 256, 0, stream>>>(hid, resin, nw, resout, HN);
  k_gemm<0><<<dim3(ROWS / 128, DIP_PAD / 128), 256, 0, stream>>>(HN, W1b, DMODEL, nullptr, ZB,
                                                                 XBC, DT, dtb);
  k_conv<<<(ROWS * 272) / 256, 256, 0, stream>>>(XBC, cw, cb, XC, BM, CM);
  k_ssd<<<256, 256, 0, stream>>>(XC, BM, CM, DT, alog, YB0, YB1);
  k_cast<<<(DMODEL * DINNER) / 1024, 256, 0, stream>>>(w2, W2b);
  k_deff<<<ROWS / 2, 64, 0, stream>>>(XC, fcw, Dv, DE);
  k_gate<<<ROWS, 256, 0, stream>>>(YB0, YB1, XC, DE, ZB, gnw, YN);
  k_gemm<1><<<dim3(ROWS / 128, DMODEL / 128), 256, 0, stream>>>(YN, W2b, DINNER, out, nullptr,
                                                                nullptr, nullptr, nullptr);
}

// Round 3
// 808.017 us; speedup vs baseline: 1.8774x; 1.0538x over previous
//
#include <hip/hip_runtime.h>

typedef __attribute__((ext_vector_type(4))) float f32x4;
typedef __attribute__((ext_vector_type(8))) short short8;
typedef __attribute__((ext_vector_type(8))) unsigned short ushort8;
typedef unsigned short u16;
typedef unsigned int u32;

#define DMODEL 1024
#define DINNER 2048
#define NH     32
#define DIP    4288
#define DIP_PAD 4352
#define CONVD  2176
#define LSEQ   2048
#define ROWS   8192
#define NCHUNK 32

static __device__ __forceinline__ float bf2f(u16 u) {
  u32 x = ((u32)u) << 16;
  return __builtin_bit_cast(float, x);
}
static __device__ __forceinline__ u16 f2bf(float f) {
  u32 x = __builtin_bit_cast(u32, f);
  x += 0x7fffu + ((x >> 16) & 1u);
  return (u16)(x >> 16);
}
static __device__ __forceinline__ f32x4 mfma16(short8 a, short8 b, f32x4 c) {
  return __builtin_amdgcn_mfma_f32_16x16x32_bf16(a, b, c, 0, 0, 0);
}

#define GLDS(gp, lp)                                                     \
  __builtin_amdgcn_global_load_lds(                                     \
      (const __attribute__((address_space(1))) void*)(gp),              \
      (__attribute__((address_space(3))) void*)(lp), 16, 0, 0)

// ---------------- f32 -> bf16 weight cast ----------------
__global__ __launch_bounds__(256) void k_cast(const float* __restrict__ s, u16* __restrict__ d) {
  size_t i = ((size_t)blockIdx.x * 256 + threadIdx.x) * 4;
  float4 v = *(const float4*)(s + i);
  u32 lo = (u32)f2bf(v.x) | ((u32)f2bf(v.y) << 16);
  u32 hi = (u32)f2bf(v.z) | ((u32)f2bf(v.w) << 16);
  *(uint2*)(d + i) = make_uint2(lo, hi);
}

// ---------------- res = h + r ; hnorm = rmsnorm(res)*w (bf16) ----------------
__global__ __launch_bounds__(256) void k_addnorm(const float* __restrict__ h,
                                                 const float* __restrict__ r,
                                                 const float* __restrict__ nw,
                                                 float* __restrict__ res,
                                                 u16* __restrict__ hn) {
  int row = blockIdx.x, t = threadIdx.x;
  const float4* hp = (const float4*)(h + (size_t)row * DMODEL);
  const float4* rp = (const float4*)(r + (size_t)row * DMODEL);
  float4 a = hp[t], b = rp[t];
  float4 s;
  s.x = a.x + b.x; s.y = a.y + b.y; s.z = a.z + b.z; s.w = a.w + b.w;
  ((float4*)(res + (size_t)row * DMODEL))[t] = s;
  float ss = s.x * s.x + s.y * s.y + s.z * s.z + s.w * s.w;
  for (int m = 32; m; m >>= 1) ss += __shfl_xor(ss, m);
  __shared__ float wsum[4];
  if ((t & 63) == 0) wsum[t >> 6] = ss;
  __syncthreads();
  float tot = wsum[0] + wsum[1] + wsum[2] + wsum[3];
  float rinv = rsqrtf(tot * (1.0f / DMODEL) + 1e-5f);
  float4 w4 = ((const float4*)nw)[t];
  u32 lo = (u32)f2bf(s.x * rinv * w4.x) | ((u32)f2bf(s.y * rinv * w4.y) << 16);
  u32 hi = (u32)f2bf(s.z * rinv * w4.z) | ((u32)f2bf(s.w * rinv * w4.w) << 16);
  *(uint2*)(hn + (size_t)row * DMODEL + t * 4) = make_uint2(lo, hi);
}

// ---------------- LDS-staged bf16 MFMA GEMM, 2-phase double-buffered ----------------
// 128x128 tile, BK=32, 4 waves (2x2), each wave 64x64 via 4x4 mfma_16x16x32.
// Pipeline: STAGE(t+1) issued BEFORE reading/computing tile t; the implicit
// vmcnt(0)+barrier at loop end lands after ~1 tile of compute -> latency hidden.
template <int MODE>
__global__ __launch_bounds__(256) void k_gemm(const u16* __restrict__ A,
                                              const u16* __restrict__ Bw, int K,
                                              float* __restrict__ outf,
                                              u16* __restrict__ zb, u16* __restrict__ xb,
                                              float* __restrict__ dtp,
                                              const float* __restrict__ dt_bias) {
  __shared__ u16 sA[2][128 * 32];
  __shared__ u16 sB[2][128 * 32];
  const int tid = threadIdx.x, wave = tid >> 6;
  const int lane = tid & 63;
  const int wm = wave >> 1, wn = wave & 1;
  const int lr = lane & 15, lg = lane >> 4;
  const int brow = blockIdx.x * 128, bcol = blockIdx.y * 128;
  const int srow = tid >> 2, scol = (tid & 3) * 8;
  const u16* gA = A + (size_t)(brow + srow) * K + scol;
  const u16* gB = Bw + (size_t)(bcol + srow) * K + scol;
  const size_t rstep = (size_t)64 * K;
  const int nk = K >> 5;

  f32x4 acc[4][4] = {};

  auto STAGE = [&](int buf, int k0) {
    char* lA = (char*)(&sA[buf][0]) + wave * 1024;
    char* lB = (char*)(&sB[buf][0]) + wave * 1024;
    GLDS(gA + k0, lA);
    GLDS(gA + rstep + k0, lA + 4096);
    GLDS(gB + k0, lB);
    GLDS(gB + rstep + k0, lB + 4096);
  };

  STAGE(0, 0);
  __syncthreads();
  for (int t = 0; t < nk; ++t) {
    const int cur = t & 1;
    if (t + 1 < nk) STAGE(cur ^ 1, (t + 1) << 5);
    short8 af[4], bf[4];
#pragma unroll
    for (int i = 0; i < 4; ++i) {
      af[i] = *(const short8*)&sA[cur][(wm * 64 + i * 16 + lr) * 32 + lg * 8];
      bf[i] = *(const short8*)&sB[cur][(wn * 64 + i * 16 + lr) * 32 + lg * 8];
    }
#pragma unroll
    for (int i = 0; i < 4; ++i)
#pragma unroll
      for (int j = 0; j < 4; ++j) acc[i][j] = mfma16(af[i], bf[j], acc[i][j]);
    __syncthreads();
  }

  const int mb = brow + wm * 64 + lg * 4;
  const int nb = bcol + wn * 64 + lr;
#pragma unroll
  for (int i = 0; i < 4; ++i)
#pragma unroll
    for (int j = 0; j < 4; ++j)
#pragma unroll
      for (int rr = 0; rr < 4; ++rr) {
        int m = mb + i * 16 + rr;
        int n = nb + j * 16;
        float v = acc[i][j][rr];
        if constexpr (MODE == 1) {
          outf[(size_t)m * 1024 + n] = v;
        } else {
          if (n < DINNER) {
            zb[(size_t)m * DINNER + n] = f2bf(v);
          } else if (n < DINNER + CONVD) {
            xb[(size_t)m * CONVD + (n - DINNER)] = f2bf(v);
          } else if (n < DIP) {
            int h2 = n - (DINNER + CONVD);  // 0..63
            float uu = v + dt_bias[h2 & 31];
            float sp = (uu > 20.f) ? uu : log1pf(expf(uu));
            int bb = m >> 11, tt = m & 2047;
            int obb = bb, ot = tt;
            if (h2 >= 32) { obb = bb + 4; ot = 2047 - tt; }
            dtp[((size_t)(obb << 11) + ot) * NH + (h2 & 31)] = sp;
          }
        }
      }
}

// ---------------- depthwise causal conv (k=4) + SiLU, 8 chans/thread ----------------
__global__ __launch_bounds__(256) void k_conv(const u16* __restrict__ xbc,
                                              const float* __restrict__ cw,
                                              const float* __restrict__ cb,
                                              u16* __restrict__ xc, u16* __restrict__ bm,
                                              u16* __restrict__ cm) {
  int e = blockIdx.x * 256 + threadIdx.x;  // e < ROWS*272
  int c8 = e % 272;
  int r = e / 272;
  int c = c8 * 8;
  int b = r >> 11, t = r & 2047;
  float4 w[8];
  float a[8];
#pragma unroll
  for (int j = 0; j < 8; ++j) {
    w[j] = *(const float4*)&cw[(c + j) * 4];
    a[j] = cb[c + j];
  }
  const u16* base = xbc + (size_t)(b << 11) * CONVD + c;
#pragma unroll
  for (int k = 0; k < 4; ++k) {
    int tt = t - 3 + k;
    if (tt >= 0) {
      ushort8 v = *(const ushort8*)(base + (size_t)tt * CONVD);
#pragma unroll
      for (int j = 0; j < 8; ++j) a[j] += bf2f(v[j]) * ((const float*)&w[j])[k];
    }
  }
  ushort8 o;
#pragma unroll
  for (int j = 0; j < 8; ++j) {
    float s = a[j] * (1.f / (1.f + expf(-a[j])));
    o[j] = f2bf(s);
  }
  if (c8 < 256) *(ushort8*)(xc + (size_t)r * DINNER + c) = o;
  else if (c8 < 264) *(ushort8*)(bm + (size_t)r * 64 + (c - DINNER)) = o;
  else *(ushort8*)(cm + (size_t)r * 64 + (c - DINNER - 64)) = o;
}

// ---------------- fused SSD scan: one block per (dir, batch, head) ----------------
__global__ __launch_bounds__(256) void k_ssd(const u16* __restrict__ xc,
                                             const u16* __restrict__ bmat,
                                             const u16* __restrict__ cmat,
                                             const float* __restrict__ dtp,
                                             const float* __restrict__ alog,
                                             u16* __restrict__ y0, u16* __restrict__ y1) {
  const int h = blockIdx.x & 31;
  const int grp = blockIdx.x >> 5;  // 0..7
  const int dir = grp >> 2;
  const int bt = grp & 3;
  const int tid = threadIdx.x, wave = tid >> 6, lane = tid & 63;
  const float Ah = -expf(alog[h]);

  __shared__ u16 sB[64][72];   // [s][n]
  __shared__ u16 sC[64][72];   // [s][n]
  __shared__ u16 sXM[64][72];  // staged X [s][p]; after transpose reused as M [l][s]
  __shared__ u16 sXT[64][72];  // X^T [p][s]
  __shared__ u16 sBT[64][72];  // B^T [n][s]
  __shared__ float sS[64][68]; // [p][n] running inter-chunk state (f32)
  __shared__ float sAc[64], sEA[64], sSc[64], sDt[64];

  for (int i = tid; i < 64 * 64; i += 256) sS[i >> 6][i & 63] = 0.f;

  const int lr = lane & 15, lg = lane >> 4;
  const int srow = tid >> 2, q = tid & 3;
  const int tp = tid >> 2, ts0 = (tid & 3) << 4;  // transpose mapping

  for (int c = 0; c < NCHUNK; ++c) {
    // ---- P0: stage B, C, X tiles + dt scan ----
    {
      int tdir = c * 64 + srow;
      int rg = bt * LSEQ + (dir ? (LSEQ - 1 - tdir) : tdir);
      const u16* bsrc = bmat + (size_t)rg * 64 + q * 16;
      const u16* csrc = cmat + (size_t)rg * 64 + q * 16;
      const u16* xsrc = xc + (size_t)rg * DINNER + h * 64 + q * 16;
      *(ushort8*)&sB[srow][q * 16] = *(const ushort8*)bsrc;
      *(ushort8*)&sB[srow][q * 16 + 8] = *(const ushort8*)(bsrc + 8);
      *(ushort8*)&sC[srow][q * 16] = *(const ushort8*)csrc;
      *(ushort8*)&sC[srow][q * 16 + 8] = *(const ushort8*)(csrc + 8);
      *(ushort8*)&sXM[srow][q * 16] = *(const ushort8*)xsrc;
      *(ushort8*)&sXM[srow][q * 16 + 8] = *(const ushort8*)(xsrc + 8);
    }
    if (tid < 64) {
      int s = tid;
      float dv = dtp[((size_t)grp * LSEQ + c * 64 + s) * NH + h];
      float a = dv * Ah;
      float x = a;
#pragma unroll
      for (int d = 1; d < 64; d <<= 1) {
        float y = __shfl_up(x, d);
        if (s >= d) x += y;
      }
      float tot = __shfl(x, 63);
      sAc[s] = x;
      sEA[s] = expf(x);
      sSc[s] = expf(tot - x) * dv;  // decay * dt
      sDt[s] = dv;
    }
    __syncthreads();

    // ---- P0b: transpose X and B into row-readable layouts ----
    {
      ushort8 vx0, vx1, vb0, vb1;
#pragma unroll
      for (int i = 0; i < 8; ++i) {
        vx0[i] = sXM[ts0 + i][tp];
        vx1[i] = sXM[ts0 + 8 + i][tp];
        vb0[i] = sB[ts0 + i][tp];
        vb1[i] = sB[ts0 + 8 + i][tp];
      }
      *(ushort8*)&sXT[tp][ts0] = vx0;
      *(ushort8*)&sXT[tp][ts0 + 8] = vx1;
      *(ushort8*)&sBT[tp][ts0] = vb0;
      *(ushort8*)&sBT[tp][ts0 + 8] = vb1;
    }
    __syncthreads();

    // ---- PA: G = C @ B^T -> M (into sXM); Yoff = C @ S_prev^T ----
    f32x4 acc_y[4] = {};
    {
      f32x4 acc_g[4] = {};
#pragma unroll
      for (int ks = 0; ks < 2; ++ks) {
        int kof = ks * 32 + lg * 8;
        short8 af = *(const short8*)&sC[wave * 16 + lr][kof];
#pragma unroll
        for (int nt = 0; nt < 4; ++nt) {
          short8 bf = *(const short8*)&sB[nt * 16 + lr][kof];
          acc_g[nt] = mfma16(af, bf, acc_g[nt]);
        }
      }
#pragma unroll
      for (int ks = 0; ks < 2; ++ks) {
        int kof = ks * 32 + lg * 8;
        short8 af = *(const short8*)&sC[wave * 16 + lr][kof];
#pragma unroll
        for (int nt = 0; nt < 4; ++nt) {
          const float* sr = &sS[nt * 16 + lr][kof];
          f32x4 s0 = *(const f32x4*)sr;
          f32x4 s1 = *(const f32x4*)(sr + 4);
          short8 bf;
#pragma unroll
          for (int e = 0; e < 4; ++e) {
            bf[e] = (short)f2bf(s0[e]);
            bf[e + 4] = (short)f2bf(s1[e]);
          }
          acc_y[nt] = mfma16(af, bf, acc_y[nt]);
        }
      }
      // masked decay matrix M[l][s] -> sXM (sXM's X content is dead: sXT holds it)
#pragma unroll
      for (int nt = 0; nt < 4; ++nt)
#pragma unroll
        for (int rr = 0; rr < 4; ++rr) {
          int l = wave * 16 + lg * 4 + rr;
          int s = nt * 16 + lr;
          float g = acc_g[nt][rr];
          float m = (l >= s) ? g * sDt[s] * expf(sAc[l] - sAc[s]) : 0.f;
          sXM[l][s] = f2bf(m);
        }
    }
    __syncthreads();

    // ---- PB: Y = Yoff*exp(Acum) + M @ X; write Y; S update ----
#pragma unroll
    for (int nt = 0; nt < 4; ++nt)
#pragma unroll
      for (int rr = 0; rr < 4; ++rr) acc_y[nt][rr] *= sEA[wave * 16 + lg * 4 + rr];
#pragma unroll
    for (int ks = 0; ks < 2; ++ks) {
      int kof = ks * 32 + lg * 8;
      short8 af = *(const short8*)&sXM[wave * 16 + lr][kof];
#pragma unroll
      for (int nt = 0; nt < 4; ++nt) {
        short8 bf = *(const short8*)&sXT[nt * 16 + lr][kof];
        acc_y[nt] = mfma16(af, bf, acc_y[nt]);
      }
    }
#pragma unroll
    for (int nt = 0; nt < 4; ++nt)
#pragma unroll
      for (int rr = 0; rr < 4; ++rr) {
        int l = wave * 16 + lg * 4 + rr;
        int p = nt * 16 + lr;
        int tg = c * 64 + l;
        if (tg <= LSEQ - 2) {
          float v = acc_y[nt][rr];
          if (dir == 0)
            y0[((size_t)bt * LSEQ + tg + 1) * DINNER + h * 64 + p] = f2bf(v);
          else
            y1[((size_t)bt * LSEQ + (LSEQ - 2 - tg)) * DINNER + h * 64 + p] = f2bf(v);
        }
      }
    if (c == 0 && tid < 64) {
      if (dir == 0)
        y0[((size_t)bt * LSEQ) * DINNER + h * 64 + tid] = 0;
      else
        y1[((size_t)bt * LSEQ + (LSEQ - 1)) * DINNER + h * 64 + tid] = 0;
    }
    // chunk state: S_new = exp(Asum)*S + (X*decay*dt)^T @ B
    {
      f32x4 acc_s[4] = {};
#pragma unroll
      for (int ks = 0; ks < 2; ++ks) {
        int kof = ks * 32 + lg * 8;
        ushort8 xr = *(const ushort8*)&sXT[wave * 16 + lr][kof];
        short8 af;
#pragma unroll
        for (int e = 0; e < 8; ++e) af[e] = (short)f2bf(bf2f(xr[e]) * sSc[kof + e]);
#pragma unroll
        for (int nt = 0; nt < 4; ++nt) {
          short8 bf = *(const short8*)&sBT[nt * 16 + lr][kof];
          acc_s[nt] = mfma16(af, bf, acc_s[nt]);
        }
      }
      float lam = sEA[63];
#pragma unroll
      for (int nt = 0; nt < 4; ++nt)
#pragma unroll
        for (int rr = 0; rr < 4; ++rr) {
          int p = wave * 16 + lg * 4 + rr;
          int n = nt * 16 + lr;
          sS[p][n] = lam * sS[p][n] + acc_s[nt][rr];
        }
    }
    __syncthreads();
  }
}

// ---------------- Deff = x @ fc_D_w^T + D ----------------
__global__ __launch_bounds__(64) void k_deff(const u16* __restrict__ xcv,
                                             const float* __restrict__ fw,
                                             const float* __restrict__ Dv,
                                             float* __restrict__ deff) {
  int r = blockIdx.x * 2 + (threadIdx.x >> 5);
  int hh = threadIdx.x & 31;
  const u16* xr = xcv + (size_t)r * DINNER;
  const float* fr = fw + (size_t)hh * DINNER;
  float acc = 0.f;
  for (int k = 0; k < DINNER; k += 8) {
    ushort8 xv = *(const ushort8*)(xr + k);
    float4 f0 = *(const float4*)(fr + k);
    float4 f1 = *(const float4*)(fr + k + 4);
    acc += bf2f(xv[0]) * f0.x + bf2f(xv[1]) * f0.y + bf2f(xv[2]) * f0.z + bf2f(xv[3]) * f0.w +
           bf2f(xv[4]) * f1.x + bf2f(xv[5]) * f1.y + bf2f(xv[6]) * f1.z + bf2f(xv[7]) * f1.w;
  }
  deff[(size_t)r * NH + hh] = acc + Dv[hh];
}

// ---------------- gating: yn = rmsnorm((y0 + y1 + x*Deff) * silu(z)) * gnw ----------------
__global__ __launch_bounds__(256) void k_gate(const u16* __restrict__ yb0,
                                              const u16* __restrict__ yb1,
                                              const u16* __restrict__ xcv,
                                              const float* __restrict__ deff,
                                              const u16* __restrict__ zb,
                                              const float* __restrict__ gnw,
                                              u16* __restrict__ yn) {
  int row = blockIdx.x, t = threadIdx.x;
  size_t base = (size_t)row * DINNER + t * 8;
  ushort8 y0v = *(const ushort8*)(yb0 + base);
  ushort8 y1v = *(const ushort8*)(yb1 + base);
  ushort8 xv = *(const ushort8*)(xcv + base);
  ushort8 zv = *(const ushort8*)(zb + base);
  float de = deff[row * NH + (t >> 3)];
  float g[8];
  float ss = 0.f;
#pragma unroll
  for (int j = 0; j < 8; ++j) {
    float y = bf2f(y0v[j]) + bf2f(y1v[j]) + bf2f(xv[j]) * de;
    float z = bf2f(zv[j]);
    float gg = y * (z / (1.f + expf(-z)));
    g[j] = gg;
    ss += gg * gg;
  }
  for (int m = 32; m; m >>= 1) ss += __shfl_xor(ss, m);
  __shared__ float wsum[4];
  if ((t & 63) == 0) wsum[t >> 6] = ss;
  __syncthreads();
  float tot = wsum[0] + wsum[1] + wsum[2] + wsum[3];
  float rinv = rsqrtf(tot * (1.0f / DINNER) + 1e-5f);
  u32 w0 = (u32)f2bf(g[0] * rinv * gnw[t * 8 + 0]) | ((u32)f2bf(g[1] * rinv * gnw[t * 8 + 1]) << 16);
  u32 w1 = (u32)f2bf(g[2] * rinv * gnw[t * 8 + 2]) | ((u32)f2bf(g[3] * rinv * gnw[t * 8 + 3]) << 16);
  u32 w2 = (u32)f2bf(g[4] * rinv * gnw[t * 8 + 4]) | ((u32)f2bf(g[5] * rinv * gnw[t * 8 + 5]) << 16);
  u32 w3 = (u32)f2bf(g[6] * rinv * gnw[t * 8 + 6]) | ((u32)f2bf(g[7] * rinv * gnw[t * 8 + 7]) << 16);
  *(uint4*)(yn + base) = make_uint4(w0, w1, w2, w3);
}

extern "C" void kernel_launch(void* const* d_in, const int* in_sizes, int n_in,
                              void* d_out, int out_size, void* d_ws, size_t ws_size,
                              hipStream_t stream) {
  (void)in_sizes; (void)n_in; (void)out_size; (void)ws_size;
  const float* hid = (const float*)d_in[0];
  const float* resin = (const float*)d_in[1];
  const float* nw = (const float*)d_in[2];
  const float* w1 = (const float*)d_in[3];
  const float* cw = (const float*)d_in[4];
  const float* cb = (const float*)d_in[5];
  const float* dtb = (const float*)d_in[6];
  const float* alog = (const float*)d_in[7];
  const float* Dv = (const float*)d_in[8];
  const float* fcw = (const float*)d_in[9];
  const float* gnw = (const float*)d_in[10];
  const float* w2 = (const float*)d_in[11];
  float* out = (float*)d_out;
  float* resout = out + (size_t)ROWS * DMODEL;

  char* ws = (char*)d_ws;
  size_t o = 0;
  auto alloc = [&](size_t bytes) {
    char* p = ws + o;
    o += (bytes + 255) & ~(size_t)255;
    return p;
  };
  u16* W1b = (u16*)alloc((size_t)DIP_PAD * DMODEL * 2);  // 8.9 MB (reused for W2b)
  u16* HN = (u16*)alloc((size_t)ROWS * DMODEL * 2);      // 16.8 MB (reused for YN)
  u16* XBC = (u16*)alloc((size_t)ROWS * CONVD * 2);      // 35.7 MB (reused for YB0)
  u16* ZB = (u16*)alloc((size_t)ROWS * DINNER * 2);      // 33.6 MB
  u16* XC = (u16*)alloc((size_t)ROWS * DINNER * 2);      // 33.6 MB
  u16* BM = (u16*)alloc((size_t)ROWS * 64 * 2);          // 1 MB
  u16* CM = (u16*)alloc((size_t)ROWS * 64 * 2);          // 1 MB
  float* DT = (float*)alloc((size_t)8 * LSEQ * NH * 4);  // 2 MB
  float* DE = (float*)alloc((size_t)ROWS * NH * 4);      // 1 MB
  u16* YB0 = XBC;
  u16* YB1 = (u16*)out;  // out region (33.55 MB) is dead until final GEMM
  u16* W2b = W1b;
  u16* YN = HN;

  k_cast<<<(DIP * DMODEL) / 1024, 256, 0, stream>>>(w1, W1b);
  k_addnorm<<<ROWS, 256, 0, stream>>>(hid, resin, nw, resout, HN);
  k_gemm<0><<<dim3(ROWS / 128, DIP_PAD / 128), 256, 0, stream>>>(HN, W1b, DMODEL, nullptr, ZB,
                                                                 XBC, DT, dtb);
  k_conv<<<(ROWS * 272) / 256, 256, 0, stream>>>(XBC, cw, cb, XC, BM, CM);
  k_ssd<<<256, 256, 0, stream>>>(XC, BM, CM, DT, alog, YB0, YB1);
  k_cast<<<(DMODEL * DINNER) / 1024, 256, 0, stream>>>(w2, W2b);
  k_deff<<<ROWS / 2, 64, 0, stream>>>(XC, fcw, Dv, DE);
  k_gate<<<ROWS, 256, 0, stream>>>(YB0, YB1, XC, DE, ZB, gnw, YN);
  k_gemm<1><<<dim3(ROWS / 128, DMODEL / 128), 256, 0, stream>>>(YN, W2b, DINNER, out, nullptr,
                                                                nullptr, nullptr, nullptr);
}